// Round 3
// baseline (617.899 us; speedup 1.0000x reference)
//
#include <hip/hip_runtime.h>

// ---------------------------------------------------------------------------
// IterNorm (ZCA whitening via Newton-Schulz), X = [128, 256, 28, 28] fp32.
//   x[c,k] = X[b,c,hw], k = b*784+hw, m = 100352
//   Sigma = eps*I + x@x^T/m - mu*mu^T ; Sigma_N = Sigma/tr(Sigma)
//   P_{k+1} = 1.5P - 0.5 P^3 Sigma_N (10 steps, P0=I); wm = P*sqrt(1/tr)
//   out[b,c,hw] = sum_c' wm[c,c'] x[b,c',hw] - (wm@mu)[c]
// All big matmuls: bf16 hi/lo split MFMA (hi*hi + hi*lo + lo*hi) ~ fp32 accuracy.
// ---------------------------------------------------------------------------

#define HW 784
#define BHW 200704          // 256*784
#define INV_M (1.0f/100352.0f)
#define EPS_RIDGE 1e-5f

typedef __bf16 bf8 __attribute__((ext_vector_type(8)));
typedef float  f4  __attribute__((ext_vector_type(4)));

__device__ __forceinline__ f4 mfma16(bf8 a, bf8 b, f4 c){
  return __builtin_amdgcn_mfma_f32_16x16x32_bf16(a, b, c, 0, 0, 0);
}

__device__ __forceinline__ unsigned short f2bf_rne(float f){
  unsigned u = __builtin_bit_cast(unsigned, f);
  return (unsigned short)((u + 0x7fffu + ((u >> 16) & 1u)) >> 16);
}
__device__ __forceinline__ float bf2f(unsigned short h){
  unsigned u = ((unsigned)h) << 16;
  return __builtin_bit_cast(float, u);
}
__device__ __forceinline__ void split_bf(float f, unsigned short& h, unsigned short& l){
  h = f2bf_rne(f);
  float r = f - bf2f(h);   // exact (Sterbenz)
  l = f2bf_rne(r);
}

// ---------------------------------------------------------------------------
// Kernel 1: covariance raw moments. grid 256 (b=blk>>1, hw-half=blk&1),
// 512 thr (8 waves, 2x4 -> wave tile 128x64 of the 256x256 output).
// Stages X[256ch][32hw] -> bf16 hi/lo LDS ([256][40] pad).
// Also accumulates per-channel sums (mean) via LDS + one global atomic.
// ---------------------------------------------------------------------------
__global__ __launch_bounds__(512, 2) void cov_kernel(const float* __restrict__ X,
                                                     float* __restrict__ part,
                                                     float* __restrict__ chansum){
  __shared__ unsigned short Ah[256][40];
  __shared__ unsigned short Al[256][40];
  __shared__ float ssum[256];
  const int t = threadIdx.x;
  const int blk = blockIdx.x;
  const int b = blk >> 1;
  const int h = blk & 1;
  const int base_hw = h * 400;               // halves 400 / 384 (16B-aligned)
  const int len    = h ? 384 : 400;
  const int nsteps = h ? 12  : 13;
  const float* __restrict__ Xb = X + (size_t)b * BHW;

  if (t < 256) ssum[t] = 0.0f;

  const int lane = t & 63;
  const int wave = t >> 6;
  const int wm = wave >> 2;                  // 0..1
  const int wn = wave & 3;                   // 0..3
  const int lr = lane & 15;
  const int ko = lane >> 4;

  f4 acc[8][4];
  #pragma unroll
  for (int m = 0; m < 8; m++)
    #pragma unroll
    for (int n = 0; n < 4; n++) acc[m][n] = f4{0.f, 0.f, 0.f, 0.f};

  float csum[4] = {0.f, 0.f, 0.f, 0.f};
  const int srow = t >> 3;                   // 0..63
  const int sfq  = t & 7;                    // 0..7

  for (int ks = 0; ks < nsteps; ++ks){
    if (ks) __syncthreads();
    #pragma unroll
    for (int i = 0; i < 4; i++){
      int row = srow + i * 64;
      int hwl = ks * 32 + sfq * 4;
      float4 v = make_float4(0.f, 0.f, 0.f, 0.f);
      if (hwl < len) v = *(const float4*)&Xb[(size_t)row * HW + base_hw + hwl];
      csum[i] += v.x + v.y + v.z + v.w;
      unsigned short h0,l0,h1,l1,h2,l2,h3,l3;
      split_bf(v.x, h0, l0); split_bf(v.y, h1, l1);
      split_bf(v.z, h2, l2); split_bf(v.w, h3, l3);
      *(ushort4*)&Ah[row][sfq * 4] = make_ushort4(h0, h1, h2, h3);
      *(ushort4*)&Al[row][sfq * 4] = make_ushort4(l0, l1, l2, l3);
    }
    __syncthreads();
    bf8 bhf[4], blf[4];
    #pragma unroll
    for (int n = 0; n < 4; n++){
      int coln = wn * 64 + n * 16 + lr;
      bhf[n] = *(const bf8*)&Ah[coln][ko * 8];
      blf[n] = *(const bf8*)&Al[coln][ko * 8];
    }
    #pragma unroll
    for (int m = 0; m < 8; m++){
      int rowm = wm * 128 + m * 16 + lr;
      bf8 ahf = *(const bf8*)&Ah[rowm][ko * 8];
      bf8 alf = *(const bf8*)&Al[rowm][ko * 8];
      #pragma unroll
      for (int n = 0; n < 4; n++){
        acc[m][n] = mfma16(ahf, bhf[n], acc[m][n]);
        acc[m][n] = mfma16(ahf, blf[n], acc[m][n]);
        acc[m][n] = mfma16(alf, bhf[n], acc[m][n]);
      }
    }
  }
  // channel sums -> LDS -> global
  atomicAdd(&ssum[srow      ], csum[0]);
  atomicAdd(&ssum[srow +  64], csum[1]);
  atomicAdd(&ssum[srow + 128], csum[2]);
  atomicAdd(&ssum[srow + 192], csum[3]);
  __syncthreads();
  if (t < 256) atomicAdd(&chansum[t], ssum[t]);

  float* __restrict__ Pp = part + (size_t)blk * 65536;
  const int cr4 = (lane >> 4) * 4;
  #pragma unroll
  for (int m = 0; m < 8; m++){
    #pragma unroll
    for (int n = 0; n < 4; n++){
      int colw = wn * 64 + n * 16 + lr;
      #pragma unroll
      for (int r = 0; r < 4; r++){
        int roww = wm * 128 + m * 16 + cr4 + r;
        Pp[roww * 256 + colw] = acc[m][n][r];
      }
    }
  }
}

// ---------------------------------------------------------------------------
// Kernel 2: reduce 256 partials -> Sigma (+eps, -mu mu^T), atomic trace.
// ---------------------------------------------------------------------------
__global__ __launch_bounds__(256) void reduce_kernel(const float* __restrict__ part,
                                                     const float* __restrict__ chansum,
                                                     float* __restrict__ Sig,
                                                     float* __restrict__ trace){
  const int i = blockIdx.x;
  const int j = threadIdx.x;
  float s = 0.f;
  #pragma unroll 8
  for (int p = 0; p < 256; p++) s += part[(size_t)p * 65536 + i * 256 + j];
  float mi = chansum[i] * INV_M;
  float mj = chansum[j] * INV_M;
  float v = s * INV_M - mi * mj + ((i == j) ? EPS_RIDGE : 0.f);
  Sig[i * 256 + j] = v;
  if (i == j) atomicAdd(trace, v);
}

// ---------------------------------------------------------------------------
// Kernel 3: Sigma_N = Sigma/tr ; P1 = 1.5 I - 0.5 Sigma_N (first NS step).
// ---------------------------------------------------------------------------
__global__ __launch_bounds__(256) void prep_kernel(const float* __restrict__ Sig,
                                                   const float* __restrict__ trace,
                                                   float* __restrict__ SigN,
                                                   float* __restrict__ P1){
  const int idx = blockIdx.x * 256 + threadIdx.x;
  const float rTr = 1.0f / trace[0];
  const float sn = Sig[idx] * rTr;
  SigN[idx] = sn;
  const int i = idx >> 8, j = idx & 255;
  P1[idx] = ((i == j) ? 1.5f : 0.0f) - 0.5f * sn;
}

// ---------------------------------------------------------------------------
// Kernel 4: generic 256x256 matmul, O = alpha*(A@B) + beta*E.
// 64x64 tiles, grid (4,4,z); z selects (B0,O0)/(B1,O1) to batch 2 matmuls.
// B staged transposed ([col][k]) so B-frags are contiguous-k b128 reads.
// ---------------------------------------------------------------------------
__global__ __launch_bounds__(256) void mm256_kernel(const float* __restrict__ A,
                                                    const float* __restrict__ B0,
                                                    const float* __restrict__ B1,
                                                    float* __restrict__ O0,
                                                    float* __restrict__ O1,
                                                    const float* __restrict__ E,
                                                    float alpha, float beta){
  const float* __restrict__ B = blockIdx.z ? B1 : B0;
  float* __restrict__ O = blockIdx.z ? O1 : O0;
  __shared__ unsigned short Ah[64][40], Al[64][40], Bh[64][40], Bl[64][40];
  const int t = threadIdx.x;
  const int lane = t & 63;
  const int wave = t >> 6;                  // 0..3 (2x2)
  const int wm = wave >> 1, wn = wave & 1;
  const int lr = lane & 15, ko = lane >> 4;
  const int r0 = blockIdx.x * 64, c0 = blockIdx.y * 64;
  f4 acc[2][2];
  acc[0][0] = f4{0.f,0.f,0.f,0.f}; acc[0][1] = f4{0.f,0.f,0.f,0.f};
  acc[1][0] = f4{0.f,0.f,0.f,0.f}; acc[1][1] = f4{0.f,0.f,0.f,0.f};

  for (int ks = 0; ks < 8; ++ks){
    if (ks) __syncthreads();
    #pragma unroll
    for (int i = 0; i < 2; i++){            // A: 64 rows x 32 k
      int idx = i * 256 + t;
      int row = idx >> 3, fq = idx & 7;
      float4 v = *(const float4*)&A[(r0 + row) * 256 + ks * 32 + fq * 4];
      unsigned short h0,l0,h1,l1,h2,l2,h3,l3;
      split_bf(v.x, h0, l0); split_bf(v.y, h1, l1);
      split_bf(v.z, h2, l2); split_bf(v.w, h3, l3);
      *(ushort4*)&Ah[row][fq * 4] = make_ushort4(h0, h1, h2, h3);
      *(ushort4*)&Al[row][fq * 4] = make_ushort4(l0, l1, l2, l3);
    }
    #pragma unroll
    for (int i = 0; i < 2; i++){            // B: [32 k][64 col] -> transposed LDS
      int idx = i * 256 + t;
      int k = idx >> 4, cq = idx & 15;
      float4 v = *(const float4*)&B[(ks * 32 + k) * 256 + c0 + cq * 4];
      unsigned short hh, ll;
      split_bf(v.x, hh, ll); Bh[cq*4+0][k] = hh; Bl[cq*4+0][k] = ll;
      split_bf(v.y, hh, ll); Bh[cq*4+1][k] = hh; Bl[cq*4+1][k] = ll;
      split_bf(v.z, hh, ll); Bh[cq*4+2][k] = hh; Bl[cq*4+2][k] = ll;
      split_bf(v.w, hh, ll); Bh[cq*4+3][k] = hh; Bl[cq*4+3][k] = ll;
    }
    __syncthreads();
    #pragma unroll
    for (int m = 0; m < 2; m++){
      bf8 ahf = *(const bf8*)&Ah[wm * 32 + m * 16 + lr][ko * 8];
      bf8 alf = *(const bf8*)&Al[wm * 32 + m * 16 + lr][ko * 8];
      #pragma unroll
      for (int n = 0; n < 2; n++){
        bf8 bhf = *(const bf8*)&Bh[wn * 32 + n * 16 + lr][ko * 8];
        bf8 blf = *(const bf8*)&Bl[wn * 32 + n * 16 + lr][ko * 8];
        acc[m][n] = mfma16(ahf, bhf, acc[m][n]);
        acc[m][n] = mfma16(ahf, blf, acc[m][n]);
        acc[m][n] = mfma16(alf, bhf, acc[m][n]);
      }
    }
  }
  const int cr4 = (lane >> 4) * 4;
  #pragma unroll
  for (int m = 0; m < 2; m++)
    #pragma unroll
    for (int n = 0; n < 2; n++)
      #pragma unroll
      for (int r = 0; r < 4; r++){
        int row = r0 + wm * 32 + m * 16 + cr4 + r;
        int col = c0 + wn * 32 + n * 16 + lr;
        float v = alpha * acc[m][n][r];
        if (beta != 0.0f) v += beta * E[row * 256 + col];
        O[row * 256 + col] = v;
      }
}

// ---------------------------------------------------------------------------
// Kernel 5: wm = P*sqrt(1/tr) -> bf16 hi/lo; woff = wm @ mu (row dot).
// ---------------------------------------------------------------------------
__global__ __launch_bounds__(256) void wmprep_kernel(const float* __restrict__ P,
                                                     const float* __restrict__ trace,
                                                     const float* __restrict__ chansum,
                                                     unsigned short* __restrict__ wmhi,
                                                     unsigned short* __restrict__ wmlo,
                                                     float* __restrict__ woff){
  const int i = blockIdx.x, t = threadIdx.x;
  __shared__ float red[256];
  const float s = sqrtf(1.0f / trace[0]);
  float v = P[i * 256 + t] * s;
  unsigned short h, l;
  split_bf(v, h, l);
  wmhi[i * 256 + t] = h;
  wmlo[i * 256 + t] = l;
  red[t] = v * (chansum[t] * INV_M);
  __syncthreads();
  for (int st = 128; st > 0; st >>= 1){
    if (t < st) red[t] += red[t + st];
    __syncthreads();
  }
  if (t == 0) woff[i] = red[0];
}

// ---------------------------------------------------------------------------
// Kernel 6: whitening GEMM. out[b,c,hw] = sum_c' wm[c,c'] X[b,c',hw] - woff[c].
// grid 896 (b * 7 hw-chunks of 112), 512 thr (8 waves, wave tile 32x112).
// ---------------------------------------------------------------------------
__global__ __launch_bounds__(512, 2) void whiten_kernel(const float* __restrict__ X,
                                                        const unsigned short* __restrict__ wmhi,
                                                        const unsigned short* __restrict__ wmlo,
                                                        const float* __restrict__ woff,
                                                        float* __restrict__ out){
  __shared__ unsigned short Ahs[256][40], Als[256][40];
  __shared__ unsigned short Bhs[112][40], Bls[112][40];
  const int blk = blockIdx.x;
  const int b = blk / 7;
  const int ch = blk % 7;
  const int hw0 = ch * 112;
  const int t = threadIdx.x;
  const int lane = t & 63;
  const int wave = t >> 6;                   // rows [32w, 32w+32)
  const int lr = lane & 15, ko = lane >> 4;
  const float* __restrict__ Xb = X + (size_t)b * BHW;
  f4 acc[2][7];
  #pragma unroll
  for (int m = 0; m < 2; m++)
    #pragma unroll
    for (int n = 0; n < 7; n++) acc[m][n] = f4{0.f, 0.f, 0.f, 0.f};

  const int arow = t >> 1, aseg = t & 1;
  for (int ks = 0; ks < 8; ++ks){
    if (ks) __syncthreads();
    { // stage wm (pre-split bf16): 256 rows x 32 k
      const uint4* sh = (const uint4*)(wmhi + arow * 256 + ks * 32 + aseg * 16);
      uint4 v0 = sh[0], v1 = sh[1];
      *(uint4*)&Ahs[arow][aseg * 16]     = v0;
      *(uint4*)&Ahs[arow][aseg * 16 + 8] = v1;
      const uint4* sl = (const uint4*)(wmlo + arow * 256 + ks * 32 + aseg * 16);
      uint4 w0 = sl[0], w1 = sl[1];
      *(uint4*)&Als[arow][aseg * 16]     = w0;
      *(uint4*)&Als[arow][aseg * 16 + 8] = w1;
    }
    #pragma unroll
    for (int i = 0; i < 2; i++){            // stage X chunk [32 k][112 hw] transposed
      int idx = i * 512 + t;
      if (idx < 896){
        int k = idx / 28, q = idx % 28;
        float4 v = *(const float4*)&Xb[(size_t)(ks * 32 + k) * HW + hw0 + q * 4];
        unsigned short hh, ll;
        split_bf(v.x, hh, ll); Bhs[q*4+0][k] = hh; Bls[q*4+0][k] = ll;
        split_bf(v.y, hh, ll); Bhs[q*4+1][k] = hh; Bls[q*4+1][k] = ll;
        split_bf(v.z, hh, ll); Bhs[q*4+2][k] = hh; Bls[q*4+2][k] = ll;
        split_bf(v.w, hh, ll); Bhs[q*4+3][k] = hh; Bls[q*4+3][k] = ll;
      }
    }
    __syncthreads();
    bf8 bhf[7], blf[7];
    #pragma unroll
    for (int n = 0; n < 7; n++){
      bhf[n] = *(const bf8*)&Bhs[n * 16 + lr][ko * 8];
      blf[n] = *(const bf8*)&Bls[n * 16 + lr][ko * 8];
    }
    #pragma unroll
    for (int m = 0; m < 2; m++){
      bf8 ahf = *(const bf8*)&Ahs[wave * 32 + m * 16 + lr][ko * 8];
      bf8 alf = *(const bf8*)&Als[wave * 32 + m * 16 + lr][ko * 8];
      #pragma unroll
      for (int n = 0; n < 7; n++){
        acc[m][n] = mfma16(ahf, bhf[n], acc[m][n]);
        acc[m][n] = mfma16(ahf, blf[n], acc[m][n]);
        acc[m][n] = mfma16(alf, bhf[n], acc[m][n]);
      }
    }
  }
  const int cr4 = (lane >> 4) * 4;
  #pragma unroll
  for (int m = 0; m < 2; m++){
    #pragma unroll
    for (int r = 0; r < 4; r++){
      int c = wave * 32 + m * 16 + cr4 + r;
      float wofc = woff[c];
      #pragma unroll
      for (int n = 0; n < 7; n++){
        int hw = hw0 + n * 16 + lr;
        out[(size_t)b * BHW + (size_t)c * HW + hw] = acc[m][n][r] - wofc;
      }
    }
  }
}

// ---------------------------------------------------------------------------
// Workspace layout (bytes):
//   0          : S partials   256 * 65536 * 4 = 67,108,864
//   67108864   : chansum (256 f32) + trace (1 f32)  [zeroed each call]
//   67110912   : Sig    (256KB)
//   67373056   : SigN   (256KB)
//   67635200   : Pa     (256KB)
//   67897344   : Pb     (256KB)
//   68159488   : C1     (256KB)
//   68421632   : C2     (256KB)
//   68683776   : woff   (1KB, padded 2KB)
//   68685824   : wmhi   (128KB)
//   68816896   : wmlo   (128KB)   -> total ~65.8 MB
// ---------------------------------------------------------------------------
extern "C" void kernel_launch(void* const* d_in, const int* in_sizes, int n_in,
                              void* d_out, int out_size, void* d_ws, size_t ws_size,
                              hipStream_t stream){
  const float* X = (const float*)d_in[0];
  float* out = (float*)d_out;
  char* ws = (char*)d_ws;
  float* part    = (float*)(ws);
  float* chansum = (float*)(ws + 67108864);
  float* trace   = (float*)(ws + 67108864 + 1024);
  float* Sig     = (float*)(ws + 67110912);
  float* SigN    = (float*)(ws + 67373056);
  float* Pa      = (float*)(ws + 67635200);
  float* Pb      = (float*)(ws + 67897344);
  float* C1      = (float*)(ws + 68159488);
  float* C2      = (float*)(ws + 68421632);
  float* woff    = (float*)(ws + 68683776);
  unsigned short* wmhi = (unsigned short*)(ws + 68685824);
  unsigned short* wmlo = (unsigned short*)(ws + 68816896);

  hipMemsetAsync(ws + 67108864, 0, 2048, stream);                 // chansum + trace
  cov_kernel   <<<256, 512, 0, stream>>>(X, part, chansum);
  reduce_kernel<<<256, 256, 0, stream>>>(part, chansum, Sig, trace);
  prep_kernel  <<<256, 256, 0, stream>>>(Sig, trace, SigN, Pa);   // Pa = P after 1 NS step

  float* P = Pa; float* Pn = Pb;
  for (int it = 0; it < 9; ++it){                                 // NS steps 2..10
    mm256_kernel<<<dim3(4,4,2), 256, 0, stream>>>(P, P, SigN, C1, C2, nullptr, 1.0f, 0.0f);
    mm256_kernel<<<dim3(4,4,1), 256, 0, stream>>>(C1, C2, nullptr, Pn, nullptr, P, -0.5f, 1.5f);
    float* tmp = P; P = Pn; Pn = tmp;
  }

  wmprep_kernel<<<256, 256, 0, stream>>>(P, trace, chansum, wmhi, wmlo, woff);
  whiten_kernel<<<896, 512, 0, stream>>>(X, wmhi, wmlo, woff, out);
}

// Round 5
// 495.805 us; speedup vs baseline: 1.2463x; 1.2463x over previous
//
#include <hip/hip_runtime.h>

// ---------------------------------------------------------------------------
// IterNorm (ZCA whitening via Newton-Schulz), X = [128, 256, 28, 28] fp32.
//   Sigma = eps*I + x@x^T/m - mu*mu^T ; Sigma_N = Sigma/tr(Sigma)
//   P_{k+1} = 1.5P - 0.5 P^3 Sigma_N (10 steps); wm = P*sqrt(1/tr)
//   out[b,c,hw] = sum_c' wm[c,c'] X[b,c',hw] - (wm@mu)[c]
// Big matmuls: bf16 hi/lo split MFMA (hi*hi + hi*lo + lo*hi) ~ fp32 accuracy.
// R3 insights: NS-chain matrices are all symmetric polynomials in Sigma_N
// (commute) -> B^T = B, so ns64 stages B row-major with NO transpose and
// runs K=256 with 2 barriers/launch (was 16). whiten's 14-way-conflict
// transpose scatter replaced by in-register shfl 4x4 transpose + b64 writes.
// ---------------------------------------------------------------------------

#define HW 784
#define BHW 200704          // 256*784
#define INV_M (1.0f/100352.0f)
#define EPS_RIDGE 1e-5f

typedef __bf16 bf8 __attribute__((ext_vector_type(8)));
typedef float  f4  __attribute__((ext_vector_type(4)));

__device__ __forceinline__ f4 mfma16(bf8 a, bf8 b, f4 c){
  return __builtin_amdgcn_mfma_f32_16x16x32_bf16(a, b, c, 0, 0, 0);
}

__device__ __forceinline__ unsigned short f2bf_rne(float f){
  unsigned u = __builtin_bit_cast(unsigned, f);
  return (unsigned short)((u + 0x7fffu + ((u >> 16) & 1u)) >> 16);
}
__device__ __forceinline__ float bf2f(unsigned short h){
  unsigned u = ((unsigned)h) << 16;
  return __builtin_bit_cast(float, u);
}
__device__ __forceinline__ void split_bf(float f, unsigned short& h, unsigned short& l){
  h = f2bf_rne(f);
  float r = f - bf2f(h);   // exact
  l = f2bf_rne(r);
}

// ---------------------------------------------------------------------------
// Kernel 1: covariance raw moments (unchanged from R2; verified R3).
// ---------------------------------------------------------------------------
__global__ __launch_bounds__(512, 2) void cov_kernel(const float* __restrict__ X,
                                                     float* __restrict__ part,
                                                     float* __restrict__ chansum){
  __shared__ unsigned short Ah[256][40];
  __shared__ unsigned short Al[256][40];
  __shared__ float ssum[256];
  const int t = threadIdx.x;
  const int blk = blockIdx.x;
  const int b = blk >> 1;
  const int h = blk & 1;
  const int base_hw = h * 400;               // halves 400 / 384 (16B-aligned)
  const int len    = h ? 384 : 400;
  const int nsteps = h ? 12  : 13;
  const float* __restrict__ Xb = X + (size_t)b * BHW;

  if (t < 256) ssum[t] = 0.0f;

  const int lane = t & 63;
  const int wave = t >> 6;
  const int wm = wave >> 2;                  // 0..1
  const int wn = wave & 3;                   // 0..3
  const int lr = lane & 15;
  const int ko = lane >> 4;

  f4 acc[8][4];
  #pragma unroll
  for (int m = 0; m < 8; m++)
    #pragma unroll
    for (int n = 0; n < 4; n++) acc[m][n] = f4{0.f, 0.f, 0.f, 0.f};

  float csum[4] = {0.f, 0.f, 0.f, 0.f};
  const int srow = t >> 3;                   // 0..63
  const int sfq  = t & 7;                    // 0..7

  for (int ks = 0; ks < nsteps; ++ks){
    if (ks) __syncthreads();
    #pragma unroll
    for (int i = 0; i < 4; i++){
      int row = srow + i * 64;
      int hwl = ks * 32 + sfq * 4;
      float4 v = make_float4(0.f, 0.f, 0.f, 0.f);
      if (hwl < len) v = *(const float4*)&Xb[(size_t)row * HW + base_hw + hwl];
      csum[i] += v.x + v.y + v.z + v.w;
      unsigned short h0,l0,h1,l1,h2,l2,h3,l3;
      split_bf(v.x, h0, l0); split_bf(v.y, h1, l1);
      split_bf(v.z, h2, l2); split_bf(v.w, h3, l3);
      *(ushort4*)&Ah[row][sfq * 4] = make_ushort4(h0, h1, h2, h3);
      *(ushort4*)&Al[row][sfq * 4] = make_ushort4(l0, l1, l2, l3);
    }
    __syncthreads();
    bf8 bhf[4], blf[4];
    #pragma unroll
    for (int n = 0; n < 4; n++){
      int coln = wn * 64 + n * 16 + lr;
      bhf[n] = *(const bf8*)&Ah[coln][ko * 8];
      blf[n] = *(const bf8*)&Al[coln][ko * 8];
    }
    #pragma unroll
    for (int m = 0; m < 8; m++){
      int rowm = wm * 128 + m * 16 + lr;
      bf8 ahf = *(const bf8*)&Ah[rowm][ko * 8];
      bf8 alf = *(const bf8*)&Al[rowm][ko * 8];
      #pragma unroll
      for (int n = 0; n < 4; n++){
        acc[m][n] = mfma16(ahf, bhf[n], acc[m][n]);
        acc[m][n] = mfma16(ahf, blf[n], acc[m][n]);
        acc[m][n] = mfma16(alf, bhf[n], acc[m][n]);
      }
    }
  }
  atomicAdd(&ssum[srow      ], csum[0]);
  atomicAdd(&ssum[srow +  64], csum[1]);
  atomicAdd(&ssum[srow + 128], csum[2]);
  atomicAdd(&ssum[srow + 192], csum[3]);
  __syncthreads();
  if (t < 256) atomicAdd(&chansum[t], ssum[t]);

  float* __restrict__ Pp = part + (size_t)blk * 65536;
  const int cr4 = (lane >> 4) * 4;
  #pragma unroll
  for (int m = 0; m < 8; m++){
    #pragma unroll
    for (int n = 0; n < 4; n++){
      int colw = wn * 64 + n * 16 + lr;
      #pragma unroll
      for (int r = 0; r < 4; r++){
        int roww = wm * 128 + m * 16 + cr4 + r;
        Pp[roww * 256 + colw] = acc[m][n][r];
      }
    }
  }
}

// ---------------------------------------------------------------------------
// Kernel 2: reduce 256 partials -> Sigma (+eps, -mu mu^T), atomic trace.
// ---------------------------------------------------------------------------
__global__ __launch_bounds__(256) void reduce_kernel(const float* __restrict__ part,
                                                     const float* __restrict__ chansum,
                                                     float* __restrict__ Sig,
                                                     float* __restrict__ trace){
  const int i = blockIdx.x;
  const int j = threadIdx.x;
  float s = 0.f;
  #pragma unroll 8
  for (int p = 0; p < 256; p++) s += part[(size_t)p * 65536 + i * 256 + j];
  float mi = chansum[i] * INV_M;
  float mj = chansum[j] * INV_M;
  float v = s * INV_M - mi * mj + ((i == j) ? EPS_RIDGE : 0.f);
  Sig[i * 256 + j] = v;
  if (i == j) atomicAdd(trace, v);
}

// ---------------------------------------------------------------------------
// Kernel 3: Sigma_N = Sigma/tr ; P1 = 1.5 I - 0.5 Sigma_N.
// ---------------------------------------------------------------------------
__global__ __launch_bounds__(256) void prep_kernel(const float* __restrict__ Sig,
                                                   const float* __restrict__ trace,
                                                   float* __restrict__ SigN,
                                                   float* __restrict__ P1){
  const int idx = blockIdx.x * 256 + threadIdx.x;
  const float rTr = 1.0f / trace[0];
  const float sn = Sig[idx] * rTr;
  SigN[idx] = sn;
  const int i = idx >> 8, j = idx & 255;
  P1[idx] = ((i == j) ? 1.5f : 0.0f) - 0.5f * sn;
}

// ---------------------------------------------------------------------------
// Kernel 4: NS matmul, O = alpha*(A@B) + beta*E, all 256x256 SYMMETRIC.
// Symmetric B => B-fragments ([col][k]) read B's rows directly: no transpose.
// 64x64 tile, K=256 in two 128-halves -> 2 barriers per K-tile (was 16).
// grid (4,4,z): z batches (B0,O0)/(B1,O1).
// ---------------------------------------------------------------------------
__global__ __launch_bounds__(256) void ns64_kernel(const float* __restrict__ A,
                                                   const float* __restrict__ B0,
                                                   const float* __restrict__ B1,
                                                   float* __restrict__ O0,
                                                   float* __restrict__ O1,
                                                   const float* __restrict__ E,
                                                   float alpha, float beta){
  const float* __restrict__ B = blockIdx.z ? B1 : B0;
  float* __restrict__ O = blockIdx.z ? O1 : O0;
  __shared__ unsigned short Ah[64][136], Al[64][136], Bh[64][136], Bl[64][136];
  const int t = threadIdx.x;
  const int lane = t & 63;
  const int wave = t >> 6;                  // 0..3 (2x2)
  const int wm = wave >> 1, wn = wave & 1;
  const int lr = lane & 15, ko = lane >> 4;
  const int r0 = blockIdx.x * 64, c0 = blockIdx.y * 64;
  const int srow = t >> 2;                  // 0..63
  const int sc0 = (t & 3) * 32;             // 4 col-blocks of 32 floats
  f4 acc[2][2];
  acc[0][0] = f4{0.f,0.f,0.f,0.f}; acc[0][1] = f4{0.f,0.f,0.f,0.f};
  acc[1][0] = f4{0.f,0.f,0.f,0.f}; acc[1][1] = f4{0.f,0.f,0.f,0.f};

  for (int kh = 0; kh < 2; ++kh){
    if (kh) __syncthreads();
    #pragma unroll
    for (int i = 0; i < 8; i++){
      int col = sc0 + i * 4;                // 0..127 within half
      int gcol = kh * 128 + col;
      unsigned short h0,l0,h1,l1,h2,l2,h3,l3;
      float4 va = *(const float4*)&A[(r0 + srow) * 256 + gcol];
      split_bf(va.x,h0,l0); split_bf(va.y,h1,l1); split_bf(va.z,h2,l2); split_bf(va.w,h3,l3);
      *(ushort4*)&Ah[srow][col] = make_ushort4(h0,h1,h2,h3);
      *(ushort4*)&Al[srow][col] = make_ushort4(l0,l1,l2,l3);
      float4 vb = *(const float4*)&B[(c0 + srow) * 256 + gcol];   // symmetric: row=col-panel
      split_bf(vb.x,h0,l0); split_bf(vb.y,h1,l1); split_bf(vb.z,h2,l2); split_bf(vb.w,h3,l3);
      *(ushort4*)&Bh[srow][col] = make_ushort4(h0,h1,h2,h3);
      *(ushort4*)&Bl[srow][col] = make_ushort4(l0,l1,l2,l3);
    }
    __syncthreads();
    #pragma unroll
    for (int ks = 0; ks < 4; ++ks){
      #pragma unroll
      for (int m = 0; m < 2; m++){
        bf8 ahf = *(const bf8*)&Ah[wm * 32 + m * 16 + lr][ks * 32 + ko * 8];
        bf8 alf = *(const bf8*)&Al[wm * 32 + m * 16 + lr][ks * 32 + ko * 8];
        #pragma unroll
        for (int n = 0; n < 2; n++){
          bf8 bhf = *(const bf8*)&Bh[wn * 32 + n * 16 + lr][ks * 32 + ko * 8];
          bf8 blf = *(const bf8*)&Bl[wn * 32 + n * 16 + lr][ks * 32 + ko * 8];
          acc[m][n] = mfma16(ahf, bhf, acc[m][n]);
          acc[m][n] = mfma16(ahf, blf, acc[m][n]);
          acc[m][n] = mfma16(alf, bhf, acc[m][n]);
        }
      }
    }
  }
  const int cr4 = (lane >> 4) * 4;
  #pragma unroll
  for (int m = 0; m < 2; m++)
    #pragma unroll
    for (int n = 0; n < 2; n++)
      #pragma unroll
      for (int r = 0; r < 4; r++){
        int row = r0 + wm * 32 + m * 16 + cr4 + r;
        int col = c0 + wn * 32 + n * 16 + lr;
        float v = alpha * acc[m][n][r];
        if (beta != 0.0f) v += beta * E[row * 256 + col];
        O[row * 256 + col] = v;
      }
}

// ---------------------------------------------------------------------------
// Kernel 5: wm = P*sqrt(1/tr) -> bf16 hi/lo; woff = wm @ mu.
// ---------------------------------------------------------------------------
__global__ __launch_bounds__(256) void wmprep_kernel(const float* __restrict__ P,
                                                     const float* __restrict__ trace,
                                                     const float* __restrict__ chansum,
                                                     unsigned short* __restrict__ wmhi,
                                                     unsigned short* __restrict__ wmlo,
                                                     float* __restrict__ woff){
  const int i = blockIdx.x, t = threadIdx.x;
  __shared__ float red[256];
  const float s = sqrtf(1.0f / trace[0]);
  float v = P[i * 256 + t] * s;
  unsigned short h, l;
  split_bf(v, h, l);
  wmhi[i * 256 + t] = h;
  wmlo[i * 256 + t] = l;
  red[t] = v * (chansum[t] * INV_M);
  __syncthreads();
  for (int st = 128; st > 0; st >>= 1){
    if (t < st) red[t] += red[t + st];
    __syncthreads();
  }
  if (t == 0) woff[i] = red[0];
}

// ---------------------------------------------------------------------------
// Kernel 6: whitening GEMM. out[b,c,hw] = sum_c' wm[c,c'] X[b,c',hw] - woff[c].
// grid 896 (b * 7 hw-chunks of 112), 512 thr.
// B-staging: in-register 4x4 shfl transpose (lane groups {l,l^16,l^32,l^48}),
// then ushort4 (b64) writes -> replaces the 14-way-conflict scalar scatter.
// LDS layout & MFMA read path unchanged.
// ---------------------------------------------------------------------------
__global__ __launch_bounds__(512, 2) void whiten_kernel(const float* __restrict__ X,
                                                        const unsigned short* __restrict__ wmhi,
                                                        const unsigned short* __restrict__ wmlo,
                                                        const float* __restrict__ woff,
                                                        float* __restrict__ out){
  __shared__ unsigned short Ahs[256][40], Als[256][40];
  __shared__ unsigned short Bhs[112][40], Bls[112][40];
  const int blk = blockIdx.x;
  const int b = blk / 7;
  const int ch = blk % 7;
  const int hw0 = ch * 112;
  const int t = threadIdx.x;
  const int lane = t & 63;
  const int wave = t >> 6;                   // rows [32w, 32w+32)
  const int lr = lane & 15, ko = lane >> 4;
  const float* __restrict__ Xb = X + (size_t)b * BHW;
  f4 acc[2][7];
  #pragma unroll
  for (int m = 0; m < 2; m++)
    #pragma unroll
    for (int n = 0; n < 7; n++) acc[m][n] = f4{0.f, 0.f, 0.f, 0.f};

  const int arow = t >> 1, aseg = t & 1;
  const int g = lane >> 4;                   // 0..3: position in shfl group
  const int cc = (t >> 4);                   // 0..31: k-index this thread loads (=4*wave+g)
  for (int ks = 0; ks < 8; ++ks){
    if (ks) __syncthreads();
    { // stage wm (pre-split bf16): 256 rows x 32 k  (unchanged)
      const uint4* sh = (const uint4*)(wmhi + arow * 256 + ks * 32 + aseg * 16);
      uint4 v0 = sh[0], v1 = sh[1];
      *(uint4*)&Ahs[arow][aseg * 16]     = v0;
      *(uint4*)&Ahs[arow][aseg * 16 + 8] = v1;
      const uint4* sl = (const uint4*)(wmlo + arow * 256 + ks * 32 + aseg * 16);
      uint4 w0 = sl[0], w1 = sl[1];
      *(uint4*)&Als[arow][aseg * 16]     = w0;
      *(uint4*)&Als[arow][aseg * 16 + 8] = w1;
    }
    // stage X chunk [32 k][112 hw] via register 4x4 transpose, 2 passes
    #pragma unroll
    for (int p = 0; p < 2; p++){
      int qh = p * 16 + (t & 15);            // hw-quad 0..27 (uniform in shfl group)
      if (qh < 28){
        float4 v = *(const float4*)&Xb[(size_t)(ks * 32 + cc) * HW + hw0 + qh * 4];
        // 4x4 transpose among lanes {l, l^16, l^32, l^48}
        float r0 = __shfl_xor((g & 1) ? v.x : v.y, 16);
        float r1 = __shfl_xor((g & 1) ? v.z : v.w, 16);
        float a0 = (g & 1) ? r0  : v.x;
        float a1 = (g & 1) ? v.y : r0;
        float a2 = (g & 1) ? r1  : v.z;
        float a3 = (g & 1) ? v.w : r1;
        float s0 = __shfl_xor((g & 2) ? a0 : a2, 32);
        float s1 = __shfl_xor((g & 2) ? a1 : a3, 32);
        float b0v = (g & 2) ? s0 : a0;
        float b1v = (g & 2) ? s1 : a1;
        float b2v = (g & 2) ? a2 : s0;
        float b3v = (g & 2) ? a3 : s1;
        // lane now holds hw-row qh*4+g, k = 4*wave + 0..3
        int row = qh * 4 + g;
        int colk = (t >> 6) * 4;             // k-base of this group
        unsigned short h0,l0,h1,l1,h2,l2,h3,l3;
        split_bf(b0v,h0,l0); split_bf(b1v,h1,l1); split_bf(b2v,h2,l2); split_bf(b3v,h3,l3);
        *(ushort4*)&Bhs[row][colk] = make_ushort4(h0,h1,h2,h3);
        *(ushort4*)&Bls[row][colk] = make_ushort4(l0,l1,l2,l3);
      }
    }
    __syncthreads();
    bf8 bhf[7], blf[7];
    #pragma unroll
    for (int n = 0; n < 7; n++){
      bhf[n] = *(const bf8*)&Bhs[n * 16 + lr][ko * 8];
      blf[n] = *(const bf8*)&Bls[n * 16 + lr][ko * 8];
    }
    #pragma unroll
    for (int m = 0; m < 2; m++){
      bf8 ahf = *(const bf8*)&Ahs[wave * 32 + m * 16 + lr][ko * 8];
      bf8 alf = *(const bf8*)&Als[wave * 32 + m * 16 + lr][ko * 8];
      #pragma unroll
      for (int n = 0; n < 7; n++){
        acc[m][n] = mfma16(ahf, bhf[n], acc[m][n]);
        acc[m][n] = mfma16(ahf, blf[n], acc[m][n]);
        acc[m][n] = mfma16(alf, bhf[n], acc[m][n]);
      }
    }
  }
  const int cr4 = (lane >> 4) * 4;
  #pragma unroll
  for (int m = 0; m < 2; m++){
    #pragma unroll
    for (int r = 0; r < 4; r++){
      int c = wave * 32 + m * 16 + cr4 + r;
      float wofc = woff[c];
      #pragma unroll
      for (int n = 0; n < 7; n++){
        int hw = hw0 + n * 16 + lr;
        out[(size_t)b * BHW + (size_t)c * HW + hw] = acc[m][n][r] - wofc;
      }
    }
  }
}

// ---------------------------------------------------------------------------
// Workspace layout (bytes): same as R2.
// ---------------------------------------------------------------------------
extern "C" void kernel_launch(void* const* d_in, const int* in_sizes, int n_in,
                              void* d_out, int out_size, void* d_ws, size_t ws_size,
                              hipStream_t stream){
  const float* X = (const float*)d_in[0];
  float* out = (float*)d_out;
  char* ws = (char*)d_ws;
  float* part    = (float*)(ws);
  float* chansum = (float*)(ws + 67108864);
  float* trace   = (float*)(ws + 67108864 + 1024);
  float* Sig     = (float*)(ws + 67110912);
  float* SigN    = (float*)(ws + 67373056);
  float* Pa      = (float*)(ws + 67635200);
  float* Pb      = (float*)(ws + 67897344);
  float* C1      = (float*)(ws + 68159488);
  float* C2      = (float*)(ws + 68421632);
  float* woff    = (float*)(ws + 68683776);
  unsigned short* wmhi = (unsigned short*)(ws + 68685824);
  unsigned short* wmlo = (unsigned short*)(ws + 68816896);

  hipMemsetAsync(ws + 67108864, 0, 2048, stream);                 // chansum + trace
  cov_kernel   <<<256, 512, 0, stream>>>(X, part, chansum);
  reduce_kernel<<<256, 256, 0, stream>>>(part, chansum, Sig, trace);
  prep_kernel  <<<256, 256, 0, stream>>>(Sig, trace, SigN, Pa);   // Pa = P after 1 NS step

  float* P = Pa; float* Pn = Pb;
  for (int it = 0; it < 9; ++it){                                 // NS steps 2..10
    ns64_kernel<<<dim3(4,4,2), 256, 0, stream>>>(P, P, SigN, C1, C2, nullptr, 1.0f, 0.0f);
    ns64_kernel<<<dim3(4,4,1), 256, 0, stream>>>(C1, C2, nullptr, Pn, nullptr, P, -0.5f, 1.5f);
    float* tmp = P; P = Pn; Pn = tmp;
  }

  wmprep_kernel<<<256, 256, 0, stream>>>(P, trace, chansum, wmhi, wmlo, woff);
  whiten_kernel<<<896, 512, 0, stream>>>(X, wmhi, wmlo, woff, out);
}